// Round 2
// baseline (168.243 us; speedup 1.0000x reference)
//
#include <hip/hip_runtime.h>
#include <math.h>

#define SIGMA_BOOST 2.0f
#define EPSILON 1e-6f

// ---------------------------------------------------------------------------
// Per-t parameters {mean_row, mean_col, sigma, pvalue}. Numerics FROZEN from
// the passing round-1 kernel (absmax 9.31 vs threshold 10.48 — index flips at
// round-half boundaries are the error source; do not perturb).
// ---------------------------------------------------------------------------
__device__ __forceinline__ float4 compute_param(const float2* __restrict__ pmeans,
                                                const float* __restrict__ psigmas,
                                                const float* __restrict__ pvalues,
                                                int t, int N) {
    float2 pm = pmeans[t];
    float scale = (float)(N - 1);
    float m0 = __fmul_rn(__fdiv_rn(1.0f, __fadd_rn(1.0f, expf(-pm.x))), scale);
    float m1 = __fmul_rn(__fdiv_rn(1.0f, __fadd_rn(1.0f, expf(-pm.y))), scale);
    float z  = __fadd_rn(psigmas[t], SIGMA_BOOST);
    float sp = __fadd_rn(fmaxf(z, 0.0f), log1pf(expf(-fabsf(z))));
    float sg = __fmul_rn(__fadd_rn(sp, EPSILON), (float)N);
    return make_float4(m0, m1, sg, pvalues[t]);
}

__global__ void params_kernel(const float2* __restrict__ pmeans,
                              const float* __restrict__ psigmas,
                              const float* __restrict__ pvalues,
                              float4* __restrict__ params, int N) {
    int t = blockIdx.x * blockDim.x + threadIdx.x;
    if (t < N) params[t] = compute_param(pmeans, psigmas, pvalues, t, N);
}

// ---------------------------------------------------------------------------
// One block per batch row b.
// STAGED=true : LDS = [y-acc N floats][x-row N floats] = 128 KB. Random x
//               gathers hit LDS (ds_read, ~free banking) instead of
//               splintered global transactions.
// STAGED=false: LDS = y-acc only (64 KB, 2 blocks/CU); gathers from global.
// UNROLL iterations are batched: all loads issued before any use → UNROLL
// outstanding misses per wave (fixes the round-1 VGPR=8 serialized chain).
// ---------------------------------------------------------------------------
template <bool STAGED, bool INLINE_PARAMS, int UNROLL>
__launch_bounds__(1024, 1)
__global__ void contract_kernel(const float* __restrict__ x,
                                const float2* __restrict__ noise,
                                const float4* __restrict__ params,
                                const float2* __restrict__ pmeans,
                                const float* __restrict__ psigmas,
                                const float* __restrict__ pvalues,
                                float* __restrict__ y, int N) {
    extern __shared__ float lds[];
    float* ly = lds;
    float* lx = STAGED ? (lds + N) : nullptr;

    const int b = blockIdx.x;
    const int tid = threadIdx.x;
    const int nthr = blockDim.x;
    const int n4 = N >> 2;

    const float* xb = x + (size_t)b * N;
    float4* ly4 = (float4*)ly;
    const float4* xb4 = (const float4*)xb;

    // zero accumulator; stage x row (coalesced float4)
    if (STAGED) {
        float4* lx4 = (float4*)lx;
        for (int i = tid; i < n4; i += nthr) {
            ly4[i] = make_float4(0.f, 0.f, 0.f, 0.f);
            lx4[i] = xb4[i];
        }
    } else {
        for (int i = tid; i < n4; i += nthr)
            ly4[i] = make_float4(0.f, 0.f, 0.f, 0.f);
    }
    __syncthreads();

    const float4* nb4 = (const float4*)(noise + (size_t)b * N); // row = N float2s
    const float fN1 = (float)(N - 1);

    for (int t0 = tid * UNROLL; t0 < N; t0 += nthr * UNROLL) {
        // --- batch: noise loads (contiguous 8*UNROLL bytes per lane) ---
        float nz[2 * UNROLL];
#pragma unroll
        for (int u = 0; u < UNROLL / 2; ++u) {
            float4 nv = nb4[(t0 >> 1) + u];
            nz[4 * u + 0] = nv.x; nz[4 * u + 1] = nv.y;
            nz[4 * u + 2] = nv.z; nz[4 * u + 3] = nv.w;
        }
        // --- batch: params ---
        float4 p[UNROLL];
#pragma unroll
        for (int u = 0; u < UNROLL; ++u)
            p[u] = INLINE_PARAMS ? compute_param(pmeans, psigmas, pvalues, t0 + u, N)
                                 : params[t0 + u];
        // --- batch: indices (sample = mean + sigma*noise, UNFUSED mul+add;
        //     rintf = half-to-even = np.round; clamp in float) ---
        int r[UNROLL], c[UNROLL];
#pragma unroll
        for (int u = 0; u < UNROLL; ++u) {
            float s0 = __fadd_rn(p[u].x, __fmul_rn(p[u].z, nz[2 * u + 0]));
            float s1 = __fadd_rn(p[u].y, __fmul_rn(p[u].z, nz[2 * u + 1]));
            r[u] = (int)fminf(fmaxf(rintf(s0), 0.0f), fN1);
            c[u] = (int)fminf(fmaxf(rintf(s1), 0.0f), fN1);
        }
        // --- batch: gathers (UNROLL independent loads in flight) ---
        float xv[UNROLL];
#pragma unroll
        for (int u = 0; u < UNROLL; ++u)
            xv[u] = STAGED ? lx[c[u]] : xb[c[u]];
        // --- batch: LDS scatter-adds ---
#pragma unroll
        for (int u = 0; u < UNROLL; ++u)
            atomicAdd(&ly[r[u]], __fmul_rn(p[u].w, xv[u]));
    }
    __syncthreads();

    // coalesced write-out
    float4* yb4 = (float4*)(y + (size_t)b * N);
    for (int i = tid; i < n4; i += nthr) yb4[i] = ly4[i];
}

extern "C" void kernel_launch(void* const* d_in, const int* in_sizes, int n_in,
                              void* d_out, int out_size, void* d_ws, size_t ws_size,
                              hipStream_t stream) {
    const float*  x       = (const float*)d_in[0];
    const float2* noise   = (const float2*)d_in[1];
    const float2* pmeans  = (const float2*)d_in[2];
    const float*  psigmas = (const float*)d_in[3];
    const float*  pvalues = (const float*)d_in[4];
    float* y = (float*)d_out;

    const int N = in_sizes[3];          // psigmas is (N,)
    const int B = in_sizes[0] / N;      // x is (B,N)

    const size_t params_bytes = (size_t)N * sizeof(float4);
    const bool use_ws = (ws_size >= params_bytes) && (d_ws != nullptr);

    const int block = 1024;
    const size_t staged_lds = 2 * (size_t)N * sizeof(float);  // 128 KB
    const size_t acc_lds    = (size_t)N * sizeof(float);      // 64 KB

    // CDNA4 LDS is 160 KB/CU; check whether the runtime allows a 128 KB
    // workgroup allocation (deterministic → graph-capture safe branching).
    int dev = 0;
    (void)hipGetDevice(&dev);
    int max_lds = 0;
    (void)hipDeviceGetAttribute(&max_lds, hipDeviceAttributeMaxSharedMemoryPerBlock, dev);
    const bool staged = (size_t)max_lds >= staged_lds;

    float4* params = (float4*)d_ws;
    if (use_ws)
        params_kernel<<<(N + 255) / 256, 256, 0, stream>>>(pmeans, psigmas, pvalues, params, N);

    if (staged) {
        if (use_ws) {
            (void)hipFuncSetAttribute(
                reinterpret_cast<const void*>(&contract_kernel<true, false, 4>),
                hipFuncAttributeMaxDynamicSharedMemorySize, (int)staged_lds);
            contract_kernel<true, false, 4><<<B, block, staged_lds, stream>>>(
                x, noise, params, nullptr, nullptr, nullptr, y, N);
        } else {
            (void)hipFuncSetAttribute(
                reinterpret_cast<const void*>(&contract_kernel<true, true, 4>),
                hipFuncAttributeMaxDynamicSharedMemorySize, (int)staged_lds);
            contract_kernel<true, true, 4><<<B, block, staged_lds, stream>>>(
                x, noise, nullptr, pmeans, psigmas, pvalues, y, N);
        }
    } else {
        if (use_ws) {
            contract_kernel<false, false, 8><<<B, block, acc_lds, stream>>>(
                x, noise, params, nullptr, nullptr, nullptr, y, N);
        } else {
            contract_kernel<false, true, 8><<<B, block, acc_lds, stream>>>(
                x, noise, nullptr, pmeans, psigmas, pvalues, y, N);
        }
    }
}